// Round 1
// 663.371 us; speedup vs baseline: 1.0068x; 1.0068x over previous
//
#include <hip/hip_runtime.h>

// LQR2: NS=32, NC=16, T=64, NB=512, NSC=48
// out: x[512][64][32] | u[512][64][16] | cost[512]
// ws:  K^T fp32 [512][64][32][16]  then k fp32 [512][64][16]
//
// R4: (a) cost computed analytically during backward; (b) solve on ONE wave
// (alternating 3/2); (c) forward = barrier-free wave-synchronous recurrence.
// R5: (a) in-loop barriers are lgkmcnt-only (inline asm) so the Q prefetch is
// no longer vmcnt(0)-drained at B1 every step — the wait lands at the commit
// after B2; (b) LDS padding: bf16 tiles rows 32->40 cols (80B = 20 banks,
// 16B-aligned rows, 8-way -> 2-way on ds_read_b128), sQ/sFf rows 48->52
// floats (208B = 20 banks); (c) ppf copy deferred past the commit.

#define NSd 32
#define NCd 16
#define Td 64
#define NBd 512
#define NSCd 48
#define SQS 52  // padded row stride (floats) for sQ / sFf
#define TP 40   // padded row stride (bf16) for MFMA tiles

typedef __bf16 bf16x8 __attribute__((ext_vector_type(8)));
typedef __bf16 bf16x4 __attribute__((ext_vector_type(4)));
typedef float f32x4 __attribute__((ext_vector_type(4)));

#define MFMA16(a, b, c) __builtin_amdgcn_mfma_f32_16x16x32_bf16(a, b, c, 0, 0, 0)

#define XOFF ((size_t)0)
#define UOFF ((size_t)NBd * Td * NSd)
#define COFF (UOFF + (size_t)NBd * Td * NCd)

__device__ __forceinline__ float rdl(float v, int l) {
  return __uint_as_float(__builtin_amdgcn_readlane(__float_as_uint(v), l));
}

// LDS-only barrier: does NOT drain vmcnt, so global prefetch loads stay in
// flight across it. All in-loop producer->consumer deps are through LDS.
__device__ __forceinline__ void bar_lgkm() {
  asm volatile("s_waitcnt lgkmcnt(0)\n\ts_barrier" ::: "memory");
}

union LdsU {
  struct {  // backward phase
    __bf16 FTh[48][TP], FTl[48][TP];
    __bf16 Vh[32][TP], Vl[32][TP];
    __bf16 WTh[48][TP], WTl[48][TP];
    __bf16 Xh[32][TP], Xl[32][TP];
    __bf16 KTh[32][TP], KTl[32][TP];
    float Quu[16][17];
    float qt[48];
    float vv[32];
    float kt[16];
  } bw;
  struct {  // forward phase (overlays dead backward fragments)
    float K2T[2][16 * 36];  // row stride 36 (bank-conflict pad, 16B aligned)
    float kv2[2][16];
    float d[32];
    float xs[32];
    float uu[16];
  } fw;
};

// padded sQ store: linear float4 index i (of 576) -> row i/12, col (i%12)*4
#define SQSTORE(i, v)                            \
  do {                                           \
    int _r = (i) / 12, _c = (i) - _r * 12;       \
    *(float4*)&sQ[_r * SQS + _c * 4] = (v);      \
  } while (0)

__global__ __launch_bounds__(256, 2) void lqr_kernel(
    const float* __restrict__ x_init, const float* __restrict__ Qg,
    const float* __restrict__ pg, const float* __restrict__ Ag,
    const float* __restrict__ Bg, float* __restrict__ out,
    float* __restrict__ wsK, float* __restrict__ wskv) {
  const int b = blockIdx.x;
  const int tid = threadIdx.x;
  const int w = tid >> 6;
  const int lane = tid & 63;
  const int fn = lane & 15;
  const int quad = lane >> 4;
  const int k0 = quad * 8;

  __shared__ __attribute__((aligned(16))) float sQ[48 * SQS];
  __shared__ __attribute__((aligned(16))) float scx[Td][NSd];
  __shared__ __attribute__((aligned(16))) float sFf[NSd][SQS];
  __shared__ __attribute__((aligned(16))) LdsU U;
  __shared__ float scostp[4];

  // ---------------- setup ----------------
  for (int idx = tid; idx < 1536; idx += 256) {
    int i = idx / 48, j = idx - i * 48;
    sFf[i][j] = (j < 32) ? Ag[i * 32 + j] : Bg[i * 16 + (j - 32)];
  }
  for (int idx = tid; idx < 1536; idx += 256) {
    int a = idx >> 5, k = idx & 31;
    float f = (a < 32) ? Ag[k * 32 + a] : Bg[k * 16 + (a - 32)];
    __bf16 h = (__bf16)f;
    U.bw.FTh[a][k] = h;
    U.bw.FTl[a][k] = (__bf16)(f - (float)h);
  }
  for (int idx = tid; idx < 1024; idx += 256) {
    int r = idx >> 5, c = idx & 31;
    __bf16 z = (__bf16)0.f;
    U.bw.Vh[r][c] = z; U.bw.Vl[r][c] = z;
    U.bw.Xh[r][c] = z; U.bw.Xl[r][c] = z;
    U.bw.KTh[r][c] = z; U.bw.KTl[r][c] = z;
  }
  if (tid < 32) {
    scx[0][tid] = x_init[b * 32 + tid];
    U.bw.vv[tid] = 0.f;
  }
  {  // stage Q[b,63]
    const float4* src = (const float4*)(Qg + ((size_t)b * Td + 63) * 2304);
    float4 v0 = src[tid];
    float4 v1 = src[tid + 256];
    SQSTORE(tid, v0);
    SQSTORE(tid + 256, v1);
    if (tid < 64) {
      float4 v2 = src[tid + 512];
      SQSTORE(tid + 512, v2);
    }
  }
  float ppf = 0.f;
  if (w == 3 && lane < 48) ppf = pg[((size_t)b * Td + 63) * 48 + lane];
  __syncthreads();

  // cx rollout, wave-0 synchronous
  if (w == 0) {
    for (int t2 = 0; t2 < Td - 1; ++t2) {
      if (lane < 32) {
        float acc = 0.f;
#pragma unroll
        for (int j = 0; j < 32; j += 4) {
          float4 a4 = *(const float4*)&sFf[lane][j];
          acc += a4.x * scx[t2][j] + a4.y * scx[t2][j + 1] +
                 a4.z * scx[t2][j + 2] + a4.w * scx[t2][j + 3];
        }
        scx[t2 + 1][lane] = acc;
      }
    }
  }
  __syncthreads();

  float cAcc = 0.f;  // w3 lanes<32: sum_t 0.5*cx'(p + 0.5*Q*cx) terms
  float dAcc = 0.f;  // solver wave lane32: sum_t 0.5*qu.kt

  // ---------------- backward Riccati: 4 barriers/step ----------------
  for (int t = Td - 1; t >= 0; --t) {
    const int sw = 3 - (t & 1);  // solver wave alternates 3,2
    float4 pf0, pf1, pf2;
    float ppfn;
    if (t > 0) {
      const float4* src = (const float4*)(Qg + ((size_t)b * Td + (t - 1)) * 2304);
      pf0 = src[tid];
      pf1 = src[tid + 256];
      if (tid < 64) pf2 = src[tid + 512];
      if (w == 3 && lane < 48) ppfn = pg[((size_t)b * Td + t - 1) * 48 + lane];
    }
    // P0: w0-2: WT = F^T V. w3: qt vector + cost const term.
    if (w < 3) {
      const int I = w;
      bf16x8 aH = *(const bf16x8*)&U.bw.FTh[16 * I + fn][k0];
      bf16x8 aL = *(const bf16x8*)&U.bw.FTl[16 * I + fn][k0];
#pragma unroll
      for (int J = 0; J < 2; ++J) {
        bf16x8 bH = *(const bf16x8*)&U.bw.Vh[16 * J + fn][k0];
        bf16x8 bL = *(const bf16x8*)&U.bw.Vl[16 * J + fn][k0];
        f32x4 acc = {0.f, 0.f, 0.f, 0.f};
        acc = MFMA16(aL, bH, acc);
        acc = MFMA16(aH, bL, acc);
        acc = MFMA16(aH, bH, acc);
#pragma unroll
        for (int r = 0; r < 4; ++r) {
          float v = acc[r];
          __bf16 h = (__bf16)v;
          U.bw.WTh[16 * I + 4 * quad + r][16 * J + fn] = h;
          U.bw.WTl[16 * I + 4 * quad + r][16 * J + fn] = (__bf16)(v - (float)h);
        }
      }
    } else if (lane < 48) {
      float acc1 = ppf;  // p + Q*cxu
#pragma unroll
      for (int k = 0; k < 32; ++k) acc1 += sQ[k * SQS + lane] * scx[t][k];
      if (lane < 32) cAcc += 0.5f * scx[t][lane] * (acc1 + ppf);
      float acc = acc1;
#pragma unroll
      for (int k = 0; k < 32; ++k) acc += U.bw.vv[k] * sFf[k][lane];
      U.bw.qt[lane] = acc;
    }
    bar_lgkm();  // B1

    // P1: Qt = Q + WT@F, 6 unique tiles over 4 waves.
    f32x4 accQ = {0.f, 0.f, 0.f, 0.f};
    if (w < 2) {
      const int I = w;
      bf16x8 aH = *(const bf16x8*)&U.bw.WTh[16 * I + fn][k0];
      bf16x8 aL = *(const bf16x8*)&U.bw.WTl[16 * I + fn][k0];
      {
        bf16x8 bH = *(const bf16x8*)&U.bw.FTh[16 * I + fn][k0];
        bf16x8 bL = *(const bf16x8*)&U.bw.FTl[16 * I + fn][k0];
#pragma unroll
        for (int r = 0; r < 4; ++r)
          accQ[r] = sQ[(16 * I + 4 * quad + r) * SQS + 16 * I + fn];
        accQ = MFMA16(aL, bH, accQ);
        accQ = MFMA16(aH, bL, accQ);
        accQ = MFMA16(aH, bH, accQ);
      }
      {
        bf16x8 bH = *(const bf16x8*)&U.bw.FTh[32 + fn][k0];
        bf16x8 bL = *(const bf16x8*)&U.bw.FTl[32 + fn][k0];
        f32x4 acc;
#pragma unroll
        for (int r = 0; r < 4; ++r)
          acc[r] = sQ[(16 * I + 4 * quad + r) * SQS + 32 + fn];
        acc = MFMA16(aL, bH, acc);
        acc = MFMA16(aH, bL, acc);
        acc = MFMA16(aH, bH, acc);
#pragma unroll
        for (int r = 0; r < 4; ++r) {
          float v = acc[r];
          __bf16 h = (__bf16)v;
          U.bw.Xh[16 * I + 4 * quad + r][fn] = h;
          U.bw.Xl[16 * I + 4 * quad + r][fn] = (__bf16)(v - (float)h);
        }
      }
    } else if (w == 2) {
      bf16x8 aH = *(const bf16x8*)&U.bw.WTh[fn][k0];
      bf16x8 aL = *(const bf16x8*)&U.bw.WTl[fn][k0];
      bf16x8 bH = *(const bf16x8*)&U.bw.FTh[16 + fn][k0];
      bf16x8 bL = *(const bf16x8*)&U.bw.FTl[16 + fn][k0];
#pragma unroll
      for (int r = 0; r < 4; ++r)
        accQ[r] = sQ[(4 * quad + r) * SQS + 16 + fn];
      accQ = MFMA16(aL, bH, accQ);
      accQ = MFMA16(aH, bL, accQ);
      accQ = MFMA16(aH, bH, accQ);
    } else {
      bf16x8 aH = *(const bf16x8*)&U.bw.WTh[32 + fn][k0];
      bf16x8 aL = *(const bf16x8*)&U.bw.WTl[32 + fn][k0];
      bf16x8 bH = *(const bf16x8*)&U.bw.FTh[32 + fn][k0];
      bf16x8 bL = *(const bf16x8*)&U.bw.FTl[32 + fn][k0];
      f32x4 acc;
#pragma unroll
      for (int r = 0; r < 4; ++r)
        acc[r] = sQ[(32 + 4 * quad + r) * SQS + 32 + fn];
      acc = MFMA16(aL, bH, acc);
      acc = MFMA16(aH, bL, acc);
      acc = MFMA16(aH, bH, acc);
#pragma unroll
      for (int r = 0; r < 4; ++r) U.bw.Quu[4 * quad + r][fn] = acc[r];
    }
    bar_lgkm();  // B2

    // commit Q prefetch (all waves; all sQ reads done). vmcnt wait lands HERE,
    // having had P0+B1+P1 to cover HBM latency.
    if (t > 0) {
      SQSTORE(tid, pf0);
      SQSTORE(tid + 256, pf1);
      if (tid < 64) SQSTORE(tid + 512, pf2);
      if (w == 3 && lane < 48) ppf = ppfn;
    }

    // P2: SOLVER WAVE ONLY: Quu * X = [Qux | qu] via readlane broadcasts.
    if (w == sw) {
      float rhs[16];
      if (lane < 32) {
        bf16x8 xh0 = *(const bf16x8*)&U.bw.Xh[lane][0];
        bf16x8 xh1 = *(const bf16x8*)&U.bw.Xh[lane][8];
        bf16x8 xl0 = *(const bf16x8*)&U.bw.Xl[lane][0];
        bf16x8 xl1 = *(const bf16x8*)&U.bw.Xl[lane][8];
#pragma unroll
        for (int i = 0; i < 8; ++i) {
          rhs[i] = (float)xh0[i] + (float)xl0[i];
          rhs[8 + i] = (float)xh1[i] + (float)xl1[i];
        }
      } else {
#pragma unroll
        for (int i = 0; i < 16; ++i) rhs[i] = U.bw.qt[32 + i];
      }
      float quu[16];
#pragma unroll
      for (int i = 0; i < 16; ++i) quu[i] = U.bw.Quu[i][fn];
#pragma unroll
      for (int r = 0; r < 15; ++r) {
        float inv = __builtin_amdgcn_rcpf(rdl(quu[r], r));
#pragma unroll
        for (int i = r + 1; i < 16; ++i) {
          float m = rdl(quu[i], r) * inv;
          rhs[i] -= m * rhs[r];
          quu[i] -= m * quu[r];
        }
      }
      float xx[16];
#pragma unroll
      for (int r = 15; r >= 0; --r) {
        float s = rhs[r];
#pragma unroll
        for (int c = r + 1; c < 16; ++c) s -= rdl(quu[r], c) * xx[c];
        xx[r] = s * __builtin_amdgcn_rcpf(rdl(quu[r], r));
      }
      if (lane < 32) {  // Kt^T bf16 to LDS + fp32 K to ws
        bf16x8 h0, l0, h1, l1;
#pragma unroll
        for (int u = 0; u < 8; ++u) {
          float kv = -xx[u];
          __bf16 hh = (__bf16)kv;
          h0[u] = hh; l0[u] = (__bf16)(kv - (float)hh);
          float kv2 = -xx[8 + u];
          __bf16 hh2 = (__bf16)kv2;
          h1[u] = hh2; l1[u] = (__bf16)(kv2 - (float)hh2);
        }
        *(bf16x8*)&U.bw.KTh[lane][0] = h0;
        *(bf16x8*)&U.bw.KTh[lane][8] = h1;
        *(bf16x8*)&U.bw.KTl[lane][0] = l0;
        *(bf16x8*)&U.bw.KTl[lane][8] = l1;
        float4* dst = (float4*)(wsK + (((size_t)b * Td + t) * 32 + lane) * 16);
        float4 v0 = {-xx[0], -xx[1], -xx[2], -xx[3]};
        float4 v1 = {-xx[4], -xx[5], -xx[6], -xx[7]};
        float4 v2 = {-xx[8], -xx[9], -xx[10], -xx[11]};
        float4 v3 = {-xx[12], -xx[13], -xx[14], -xx[15]};
        dst[0] = v0; dst[1] = v1; dst[2] = v2; dst[3] = v3;
      } else if (lane == 32) {  // kt to LDS + ws; cost Δc term
#pragma unroll
        for (int u = 0; u < 16; ++u) U.bw.kt[u] = -xx[u];
        float4* dst = (float4*)(wskv + ((size_t)b * Td + t) * 16);
        float4 v0 = {-xx[0], -xx[1], -xx[2], -xx[3]};
        float4 v1 = {-xx[4], -xx[5], -xx[6], -xx[7]};
        float4 v2 = {-xx[8], -xx[9], -xx[10], -xx[11]};
        float4 v3 = {-xx[12], -xx[13], -xx[14], -xx[15]};
        dst[0] = v0; dst[1] = v1; dst[2] = v2; dst[3] = v3;
        float s = 0.f;
#pragma unroll
        for (int i = 0; i < 16; ++i) s += U.bw.qt[32 + i] * xx[i];
        dAcc -= 0.5f * s;
      }
      if (sw == 3) {  // vn on w3 using local xx (pre-barrier)
        float acc = 0.f;
        bf16x8 xh0, xh1, xl0, xl1;
        if (lane < 32) {
          xh0 = *(const bf16x8*)&U.bw.Xh[lane][0];
          xh1 = *(const bf16x8*)&U.bw.Xh[lane][8];
          xl0 = *(const bf16x8*)&U.bw.Xl[lane][0];
          xl1 = *(const bf16x8*)&U.bw.Xl[lane][8];
          acc = U.bw.qt[lane];
        }
#pragma unroll
        for (int u = 0; u < 8; ++u) {
          float kt0 = -rdl(xx[u], 32);
          float kt1 = -rdl(xx[8 + u], 32);
          if (lane < 32) {
            acc += ((float)xh0[u] + (float)xl0[u]) * kt0;
            acc += ((float)xh1[u] + (float)xl1[u]) * kt1;
          }
        }
        if (lane < 32) U.bw.vv[lane] = acc;
      }
    }
    bar_lgkm();  // B2.5: K ready

    // P4: Vn = Qxx + Qxu @ Kt on w0-2; vn on w3 when solver was w2
    if (w == 0) {
      bf16x8 aH = *(const bf16x8*)&U.bw.Xh[fn][k0];
      bf16x8 aL = *(const bf16x8*)&U.bw.Xl[fn][k0];
      bf16x8 bH = *(const bf16x8*)&U.bw.KTh[fn][k0];
      bf16x8 bL = *(const bf16x8*)&U.bw.KTl[fn][k0];
      accQ = MFMA16(aL, bH, accQ);
      accQ = MFMA16(aH, bL, accQ);
      accQ = MFMA16(aH, bH, accQ);
#pragma unroll
      for (int r = 0; r < 4; ++r) {
        float v = accQ[r];
        __bf16 h = (__bf16)v;
        U.bw.Vh[4 * quad + r][fn] = h;
        U.bw.Vl[4 * quad + r][fn] = (__bf16)(v - (float)h);
      }
    } else if (w == 1) {
      bf16x8 aH = *(const bf16x8*)&U.bw.Xh[16 + fn][k0];
      bf16x8 aL = *(const bf16x8*)&U.bw.Xl[16 + fn][k0];
      bf16x8 bH = *(const bf16x8*)&U.bw.KTh[16 + fn][k0];
      bf16x8 bL = *(const bf16x8*)&U.bw.KTl[16 + fn][k0];
      accQ = MFMA16(aL, bH, accQ);
      accQ = MFMA16(aH, bL, accQ);
      accQ = MFMA16(aH, bH, accQ);
#pragma unroll
      for (int r = 0; r < 4; ++r) {
        float v = accQ[r];
        __bf16 h = (__bf16)v;
        U.bw.Vh[16 + 4 * quad + r][16 + fn] = h;
        U.bw.Vl[16 + 4 * quad + r][16 + fn] = (__bf16)(v - (float)h);
      }
    } else if (w == 2) {
      bf16x8 aH = *(const bf16x8*)&U.bw.Xh[fn][k0];
      bf16x8 aL = *(const bf16x8*)&U.bw.Xl[fn][k0];
      bf16x8 bH = *(const bf16x8*)&U.bw.KTh[16 + fn][k0];
      bf16x8 bL = *(const bf16x8*)&U.bw.KTl[16 + fn][k0];
      accQ = MFMA16(aL, bH, accQ);
      accQ = MFMA16(aH, bL, accQ);
      accQ = MFMA16(aH, bH, accQ);
      bf16x4 th, tl;
#pragma unroll
      for (int r = 0; r < 4; ++r) {
        float v = accQ[r];
        __bf16 h = (__bf16)v;
        __bf16 l = (__bf16)(v - (float)h);
        U.bw.Vh[4 * quad + r][16 + fn] = h;
        U.bw.Vl[4 * quad + r][16 + fn] = l;
        th[r] = h; tl[r] = l;
      }
      *(bf16x4*)&U.bw.Vh[16 + fn][4 * quad] = th;  // mirror (V symmetric)
      *(bf16x4*)&U.bw.Vl[16 + fn][4 * quad] = tl;
    } else if (sw == 2) {  // w3: vn using LDS kt
      if (lane < 32) {
        bf16x8 xh0 = *(const bf16x8*)&U.bw.Xh[lane][0];
        bf16x8 xh1 = *(const bf16x8*)&U.bw.Xh[lane][8];
        bf16x8 xl0 = *(const bf16x8*)&U.bw.Xl[lane][0];
        bf16x8 xl1 = *(const bf16x8*)&U.bw.Xl[lane][8];
        float acc = U.bw.qt[lane];
#pragma unroll
        for (int u = 0; u < 8; ++u) {
          acc += ((float)xh0[u] + (float)xl0[u]) * U.bw.kt[u];
          acc += ((float)xh1[u] + (float)xl1[u]) * U.bw.kt[8 + u];
        }
        U.bw.vv[lane] = acc;
      }
    }
    bar_lgkm();  // B3 (end of step)
  }

  // ---------------- cost partials, then union flips to forward ----------------
  if (w == 3) {
    float rv = (lane < 32) ? cAcc : 0.f;
    rv += __shfl_down(rv, 32);
    rv += __shfl_down(rv, 16);
    rv += __shfl_down(rv, 8);
    rv += __shfl_down(rv, 4);
    rv += __shfl_down(rv, 2);
    rv += __shfl_down(rv, 1);
    if (lane == 0) scostp[0] = rv;
  }
  if (lane == 32 && w >= 2) scostp[w - 1] = dAcc;  // w2->[1], w3->[2]
  // Full __syncthreads: drains wsK/wskv global stores (forward reads them via
  // global) and fences union re-use.
  __syncthreads();

  // ---------------- forward: wave-0 synchronous, barrier-free ----------------
  if (w == 0) {
    {  // preload K_0, k_0 into buf 0 (transposed, stride 36)
      const float4* src = (const float4*)(wsK + ((size_t)b * Td) * 512);
      float4 ka = src[lane * 2], kb = src[lane * 2 + 1];
      int jj = lane >> 1, ib = (lane & 1) * 8;
      float* kt2 = U.fw.K2T[0];
      kt2[(ib + 0) * 36 + jj] = ka.x; kt2[(ib + 1) * 36 + jj] = ka.y;
      kt2[(ib + 2) * 36 + jj] = ka.z; kt2[(ib + 3) * 36 + jj] = ka.w;
      kt2[(ib + 4) * 36 + jj] = kb.x; kt2[(ib + 5) * 36 + jj] = kb.y;
      kt2[(ib + 6) * 36 + jj] = kb.z; kt2[(ib + 7) * 36 + jj] = kb.w;
      if (lane < 16) U.fw.kv2[0][lane] = wskv[(size_t)b * Td * 16 + lane];
    }
    float xr = (lane < 32) ? scx[0][lane] : 0.f;
    for (int t = 0; t < Td; ++t) {
      const int cur = t & 1, nxt = cur ^ 1;
      float4 pa, pb;
      float pk;
      if (t < Td - 1) {  // prefetch K_{t+1}
        const float4* src = (const float4*)(wsK + ((size_t)b * Td + t + 1) * 512);
        pa = src[lane * 2];
        pb = src[lane * 2 + 1];
        if (lane < 16) pk = wskv[((size_t)b * Td + t + 1) * 16 + lane];
      }
      if (lane < 32) {  // d = x - cx; stash x; emit x
        U.fw.d[lane] = xr - scx[t][lane];
        U.fw.xs[lane] = xr;
        out[XOFF + ((size_t)b * Td + t) * 32 + lane] = xr;
      }
      if (lane < 16) {  // u = k + K d; emit u
        float uv = U.fw.kv2[cur][lane];
        const float* kr = &U.fw.K2T[cur][lane * 36];
#pragma unroll
        for (int j4 = 0; j4 < 8; ++j4) {
          float4 kk = *(const float4*)&kr[j4 * 4];
          float4 dd = *(const float4*)&U.fw.d[j4 * 4];
          uv += kk.x * dd.x + kk.y * dd.y + kk.z * dd.z + kk.w * dd.w;
        }
        U.fw.uu[lane] = uv;
        out[UOFF + ((size_t)b * Td + t) * 16 + lane] = uv;
      }
      if (lane < 32) {  // x' = A x + B u
        float acc = 0.f;
#pragma unroll
        for (int j4 = 0; j4 < 8; ++j4) {
          float4 ff = *(const float4*)&sFf[lane][j4 * 4];
          float4 xv = *(const float4*)&U.fw.xs[j4 * 4];
          acc += ff.x * xv.x + ff.y * xv.y + ff.z * xv.z + ff.w * xv.w;
        }
#pragma unroll
        for (int j4 = 0; j4 < 4; ++j4) {
          float4 ff = *(const float4*)&sFf[lane][32 + j4 * 4];
          float4 uv = *(const float4*)&U.fw.uu[j4 * 4];
          acc += ff.x * uv.x + ff.y * uv.y + ff.z * uv.z + ff.w * uv.w;
        }
        xr = acc;
      }
      if (t < Td - 1) {  // commit K_{t+1}
        int jj = lane >> 1, ib = (lane & 1) * 8;
        float* kt2 = U.fw.K2T[nxt];
        kt2[(ib + 0) * 36 + jj] = pa.x; kt2[(ib + 1) * 36 + jj] = pa.y;
        kt2[(ib + 2) * 36 + jj] = pa.z; kt2[(ib + 3) * 36 + jj] = pa.w;
        kt2[(ib + 4) * 36 + jj] = pb.x; kt2[(ib + 5) * 36 + jj] = pb.y;
        kt2[(ib + 6) * 36 + jj] = pb.z; kt2[(ib + 7) * 36 + jj] = pb.w;
        if (lane < 16) U.fw.kv2[nxt][lane] = pk;
      }
    }
    if (lane == 0) out[COFF + b] = scostp[0] + scostp[1] + scostp[2];
  }
}

extern "C" void kernel_launch(void* const* d_in, const int* in_sizes, int n_in,
                              void* d_out, int out_size, void* d_ws, size_t ws_size,
                              hipStream_t stream) {
  const float* x_init = (const float*)d_in[0];
  const float* Qg = (const float*)d_in[1];
  const float* pg = (const float*)d_in[2];
  const float* Ag = (const float*)d_in[3];
  const float* Bg = (const float*)d_in[4];
  float* out = (float*)d_out;
  float* wsK = (float*)d_ws;
  float* wskv = wsK + (size_t)NBd * Td * NSd * NCd;
  lqr_kernel<<<NBd, 256, 0, stream>>>(x_init, Qg, pg, Ag, Bg, out, wsK, wskv);
}

// Round 2
// 636.154 us; speedup vs baseline: 1.0499x; 1.0428x over previous
//
#include <hip/hip_runtime.h>

// LQR2: NS=32, NC=16, T=64, NB=512, NSC=48
// out: x[512][64][32] | u[512][64][16] | cost[512]
// ws:  K^T fp32 [512][64][32][16]  then k fp32 [512][64][16]
//
// R6: 2 barriers/step (was 4).
//  - P0+P1 fused: P1 tiles remapped so each wave reads only the WT rows it
//    wrote in P0 (row-block I <-> wave I). Same-wave LDS dep = lgkm only.
//  - Solver fixed to w3 (shortest phase-A job) and now also does P4 (all 3
//    Vn tiles) + vn after solving: KT LDS write->read is same-wave.
//    Register accQ tiles replaced by f32 LDS Qd[3] handoff.
//  - sQ prefetch+commit on w0-2 only (192 thr x 3 float4 = 576): solver
//    phase-B never waits on vmcnt.
// R5: lgkm-only in-loop barriers; LDS padding TP=40 bf16 / SQS=52 f32.
// R4: analytic cost during backward; wave-synchronous forward.

#define NSd 32
#define NCd 16
#define Td 64
#define NBd 512
#define NSCd 48
#define SQS 52  // padded row stride (floats) for sQ / sFf
#define TP 40   // padded row stride (bf16) for MFMA tiles

typedef __bf16 bf16x8 __attribute__((ext_vector_type(8)));
typedef __bf16 bf16x4 __attribute__((ext_vector_type(4)));
typedef float f32x4 __attribute__((ext_vector_type(4)));

#define MFMA16(a, b, c) __builtin_amdgcn_mfma_f32_16x16x32_bf16(a, b, c, 0, 0, 0)

#define XOFF ((size_t)0)
#define UOFF ((size_t)NBd * Td * NSd)
#define COFF (UOFF + (size_t)NBd * Td * NCd)

__device__ __forceinline__ float rdl(float v, int l) {
  return __uint_as_float(__builtin_amdgcn_readlane(__float_as_uint(v), l));
}

// LDS-only barrier: does NOT drain vmcnt; all in-loop cross-wave deps are LDS.
__device__ __forceinline__ void bar_lgkm() {
  asm volatile("s_waitcnt lgkmcnt(0)\n\ts_barrier" ::: "memory");
}

union LdsU {
  struct {  // backward phase
    __bf16 FTh[48][TP], FTl[48][TP];
    __bf16 Vh[32][TP], Vl[32][TP];
    __bf16 WTh[48][TP], WTl[48][TP];
    __bf16 Xh[32][TP], Xl[32][TP];
    __bf16 KTh[32][TP], KTl[32][TP];
    float Quu[16][17];
    float Qd[3][16][17];  // f32 handoff: (0,0)->0, (0,1)->1, (1,1)->2
    float qt[48];
    float vv[32];
  } bw;
  struct {  // forward phase (overlays dead backward fragments)
    float K2T[2][16 * 36];  // row stride 36 (bank-conflict pad, 16B aligned)
    float kv2[2][16];
    float d[32];
    float xs[32];
    float uu[16];
  } fw;
};

// padded sQ store: linear float4 index i (of 576) -> row i/12, col (i%12)*4
#define SQSTORE(i, v)                            \
  do {                                           \
    int _r = (i) / 12, _c = (i) - _r * 12;       \
    *(float4*)&sQ[_r * SQS + _c * 4] = (v);      \
  } while (0)

__global__ __launch_bounds__(256, 2) void lqr_kernel(
    const float* __restrict__ x_init, const float* __restrict__ Qg,
    const float* __restrict__ pg, const float* __restrict__ Ag,
    const float* __restrict__ Bg, float* __restrict__ out,
    float* __restrict__ wsK, float* __restrict__ wskv) {
  const int b = blockIdx.x;
  const int tid = threadIdx.x;
  const int w = tid >> 6;
  const int lane = tid & 63;
  const int fn = lane & 15;
  const int quad = lane >> 4;
  const int k0 = quad * 8;

  __shared__ __attribute__((aligned(16))) float sQ[48 * SQS];
  __shared__ __attribute__((aligned(16))) float scx[Td][NSd];
  __shared__ __attribute__((aligned(16))) float sFf[NSd][SQS];
  __shared__ __attribute__((aligned(16))) LdsU U;
  __shared__ float scostp[4];

  // ---------------- setup ----------------
  for (int idx = tid; idx < 1536; idx += 256) {
    int i = idx / 48, j = idx - i * 48;
    sFf[i][j] = (j < 32) ? Ag[i * 32 + j] : Bg[i * 16 + (j - 32)];
  }
  for (int idx = tid; idx < 1536; idx += 256) {
    int a = idx >> 5, k = idx & 31;
    float f = (a < 32) ? Ag[k * 32 + a] : Bg[k * 16 + (a - 32)];
    __bf16 h = (__bf16)f;
    U.bw.FTh[a][k] = h;
    U.bw.FTl[a][k] = (__bf16)(f - (float)h);
  }
  for (int idx = tid; idx < 1024; idx += 256) {
    int r = idx >> 5, c = idx & 31;
    __bf16 z = (__bf16)0.f;
    U.bw.Vh[r][c] = z; U.bw.Vl[r][c] = z;
    U.bw.Xh[r][c] = z; U.bw.Xl[r][c] = z;
    U.bw.KTh[r][c] = z; U.bw.KTl[r][c] = z;
  }
  if (tid < 32) {
    scx[0][tid] = x_init[b * 32 + tid];
    U.bw.vv[tid] = 0.f;
  }
  {  // stage Q[b,63]
    const float4* src = (const float4*)(Qg + ((size_t)b * Td + 63) * 2304);
    float4 v0 = src[tid];
    float4 v1 = src[tid + 256];
    SQSTORE(tid, v0);
    SQSTORE(tid + 256, v1);
    if (tid < 64) {
      float4 v2 = src[tid + 512];
      SQSTORE(tid + 512, v2);
    }
  }
  float ppf = 0.f;
  if (w == 3 && lane < 48) ppf = pg[((size_t)b * Td + 63) * 48 + lane];
  __syncthreads();

  // cx rollout, wave-0 synchronous
  if (w == 0) {
    for (int t2 = 0; t2 < Td - 1; ++t2) {
      if (lane < 32) {
        float acc = 0.f;
#pragma unroll
        for (int j = 0; j < 32; j += 4) {
          float4 a4 = *(const float4*)&sFf[lane][j];
          acc += a4.x * scx[t2][j] + a4.y * scx[t2][j + 1] +
                 a4.z * scx[t2][j + 2] + a4.w * scx[t2][j + 3];
        }
        scx[t2 + 1][lane] = acc;
      }
    }
  }
  __syncthreads();

  float cAcc = 0.f;  // w3 lanes<32: sum_t 0.5*cx'(p + 0.5*Q*cx) terms
  float dAcc = 0.f;  // w3 lane32: sum_t 0.5*qu.kt

  // ---------------- backward Riccati: 2 barriers/step ----------------
  for (int t = Td - 1; t >= 0; --t) {
    float4 pf0, pf1, pf2;
    float ppfn;
    if (t > 0) {
      if (w < 3) {  // 192 threads x 3 float4 = 576 = full Q tile
        const float4* src = (const float4*)(Qg + ((size_t)b * Td + (t - 1)) * 2304);
        pf0 = src[tid];
        pf1 = src[tid + 192];
        pf2 = src[tid + 384];
      } else if (lane < 48) {
        ppfn = pg[((size_t)b * Td + t - 1) * 48 + lane];
      }
    }

    // ---- Phase A: fused P0+P1 on w0-2 (wave-local WT rows); qt on w3 ----
    if (w < 3) {
      const int I = w;
      // P0: WT row-block I = F_I^T · V (both col halves)
      bf16x8 aH = *(const bf16x8*)&U.bw.FTh[16 * I + fn][k0];
      bf16x8 aL = *(const bf16x8*)&U.bw.FTl[16 * I + fn][k0];
#pragma unroll
      for (int J = 0; J < 2; ++J) {
        bf16x8 bH = *(const bf16x8*)&U.bw.Vh[16 * J + fn][k0];
        bf16x8 bL = *(const bf16x8*)&U.bw.Vl[16 * J + fn][k0];
        f32x4 acc = {0.f, 0.f, 0.f, 0.f};
        acc = MFMA16(aL, bH, acc);
        acc = MFMA16(aH, bL, acc);
        acc = MFMA16(aH, bH, acc);
#pragma unroll
        for (int r = 0; r < 4; ++r) {
          float v = acc[r];
          __bf16 h = (__bf16)v;
          U.bw.WTh[16 * I + 4 * quad + r][16 * J + fn] = h;
          U.bw.WTl[16 * I + 4 * quad + r][16 * J + fn] = (__bf16)(v - (float)h);
        }
      }
      // P1 (same wave reads only its own WT rows; lgkm dep, no barrier)
      bf16x8 wH = *(const bf16x8*)&U.bw.WTh[16 * I + fn][k0];
      bf16x8 wL = *(const bf16x8*)&U.bw.WTl[16 * I + fn][k0];
      if (I == 2) {  // (2,2) -> Quu f32
        bf16x8 bH = *(const bf16x8*)&U.bw.FTh[32 + fn][k0];
        bf16x8 bL = *(const bf16x8*)&U.bw.FTl[32 + fn][k0];
        f32x4 acc;
#pragma unroll
        for (int r = 0; r < 4; ++r)
          acc[r] = sQ[(32 + 4 * quad + r) * SQS + 32 + fn];
        acc = MFMA16(wL, bH, acc);
        acc = MFMA16(wH, bL, acc);
        acc = MFMA16(wH, bH, acc);
#pragma unroll
        for (int r = 0; r < 4; ++r) U.bw.Quu[4 * quad + r][fn] = acc[r];
      } else {
        {  // diag tile (I,I) -> Qd[0] (I=0) / Qd[2] (I=1)
          bf16x8 bH = *(const bf16x8*)&U.bw.FTh[16 * I + fn][k0];
          bf16x8 bL = *(const bf16x8*)&U.bw.FTl[16 * I + fn][k0];
          f32x4 acc;
#pragma unroll
          for (int r = 0; r < 4; ++r)
            acc[r] = sQ[(16 * I + 4 * quad + r) * SQS + 16 * I + fn];
          acc = MFMA16(wL, bH, acc);
          acc = MFMA16(wH, bL, acc);
          acc = MFMA16(wH, bH, acc);
#pragma unroll
          for (int r = 0; r < 4; ++r) U.bw.Qd[I * 2][4 * quad + r][fn] = acc[r];
        }
        if (I == 0) {  // (0,1) -> Qd[1]
          bf16x8 bH = *(const bf16x8*)&U.bw.FTh[16 + fn][k0];
          bf16x8 bL = *(const bf16x8*)&U.bw.FTl[16 + fn][k0];
          f32x4 acc;
#pragma unroll
          for (int r = 0; r < 4; ++r)
            acc[r] = sQ[(4 * quad + r) * SQS + 16 + fn];
          acc = MFMA16(wL, bH, acc);
          acc = MFMA16(wH, bL, acc);
          acc = MFMA16(wH, bH, acc);
#pragma unroll
          for (int r = 0; r < 4; ++r) U.bw.Qd[1][4 * quad + r][fn] = acc[r];
        }
        {  // (I,2) -> X rows 16I..16I+15 (Qxu block, bf16 hi/lo)
          bf16x8 bH = *(const bf16x8*)&U.bw.FTh[32 + fn][k0];
          bf16x8 bL = *(const bf16x8*)&U.bw.FTl[32 + fn][k0];
          f32x4 acc;
#pragma unroll
          for (int r = 0; r < 4; ++r)
            acc[r] = sQ[(16 * I + 4 * quad + r) * SQS + 32 + fn];
          acc = MFMA16(wL, bH, acc);
          acc = MFMA16(wH, bL, acc);
          acc = MFMA16(wH, bH, acc);
#pragma unroll
          for (int r = 0; r < 4; ++r) {
            float v = acc[r];
            __bf16 h = (__bf16)v;
            U.bw.Xh[16 * I + 4 * quad + r][fn] = h;
            U.bw.Xl[16 * I + 4 * quad + r][fn] = (__bf16)(v - (float)h);
          }
        }
      }
    } else if (lane < 48) {  // w3: qt vector + cost const term
      float acc1 = ppf;  // p + Q*cxu
#pragma unroll
      for (int k = 0; k < 32; ++k) acc1 += sQ[k * SQS + lane] * scx[t][k];
      if (lane < 32) cAcc += 0.5f * scx[t][lane] * (acc1 + ppf);
      float acc = acc1;
#pragma unroll
      for (int k = 0; k < 32; ++k) acc += U.bw.vv[k] * sFf[k][lane];
      U.bw.qt[lane] = acc;
    }
    bar_lgkm();  // B2

    // ---- Phase B: w0-2 commit sQ; w3 solves + Vn + vn ----
    if (t > 0) {
      if (w < 3) {
        SQSTORE(tid, pf0);
        SQSTORE(tid + 192, pf1);
        SQSTORE(tid + 384, pf2);
      } else if (lane < 48) {
        ppf = ppfn;
      }
    }
    if (w == 3) {
      // solve Quu * X = [Qux | qu] via readlane-broadcast elimination
      float rhs[16];
      if (lane < 32) {
        bf16x8 xh0 = *(const bf16x8*)&U.bw.Xh[lane][0];
        bf16x8 xh1 = *(const bf16x8*)&U.bw.Xh[lane][8];
        bf16x8 xl0 = *(const bf16x8*)&U.bw.Xl[lane][0];
        bf16x8 xl1 = *(const bf16x8*)&U.bw.Xl[lane][8];
#pragma unroll
        for (int i = 0; i < 8; ++i) {
          rhs[i] = (float)xh0[i] + (float)xl0[i];
          rhs[8 + i] = (float)xh1[i] + (float)xl1[i];
        }
      } else {
#pragma unroll
        for (int i = 0; i < 16; ++i) rhs[i] = U.bw.qt[32 + i];
      }
      float quu[16];
#pragma unroll
      for (int i = 0; i < 16; ++i) quu[i] = U.bw.Quu[i][fn];
#pragma unroll
      for (int r = 0; r < 15; ++r) {
        float inv = __builtin_amdgcn_rcpf(rdl(quu[r], r));
#pragma unroll
        for (int i = r + 1; i < 16; ++i) {
          float m = rdl(quu[i], r) * inv;
          rhs[i] -= m * rhs[r];
          quu[i] -= m * quu[r];
        }
      }
      float xx[16];
#pragma unroll
      for (int r = 15; r >= 0; --r) {
        float s = rhs[r];
#pragma unroll
        for (int c = r + 1; c < 16; ++c) s -= rdl(quu[r], c) * xx[c];
        xx[r] = s * __builtin_amdgcn_rcpf(rdl(quu[r], r));
      }
      if (lane < 32) {  // Kt^T bf16 to LDS + fp32 K to ws
        bf16x8 h0, l0, h1, l1;
#pragma unroll
        for (int u = 0; u < 8; ++u) {
          float kv = -xx[u];
          __bf16 hh = (__bf16)kv;
          h0[u] = hh; l0[u] = (__bf16)(kv - (float)hh);
          float kv2 = -xx[8 + u];
          __bf16 hh2 = (__bf16)kv2;
          h1[u] = hh2; l1[u] = (__bf16)(kv2 - (float)hh2);
        }
        *(bf16x8*)&U.bw.KTh[lane][0] = h0;
        *(bf16x8*)&U.bw.KTh[lane][8] = h1;
        *(bf16x8*)&U.bw.KTl[lane][0] = l0;
        *(bf16x8*)&U.bw.KTl[lane][8] = l1;
        float4* dst = (float4*)(wsK + (((size_t)b * Td + t) * 32 + lane) * 16);
        float4 v0 = {-xx[0], -xx[1], -xx[2], -xx[3]};
        float4 v1 = {-xx[4], -xx[5], -xx[6], -xx[7]};
        float4 v2 = {-xx[8], -xx[9], -xx[10], -xx[11]};
        float4 v3 = {-xx[12], -xx[13], -xx[14], -xx[15]};
        dst[0] = v0; dst[1] = v1; dst[2] = v2; dst[3] = v3;
      } else if (lane == 32) {  // kt to ws; cost delta term
        float4* dst = (float4*)(wskv + ((size_t)b * Td + t) * 16);
        float4 v0 = {-xx[0], -xx[1], -xx[2], -xx[3]};
        float4 v1 = {-xx[4], -xx[5], -xx[6], -xx[7]};
        float4 v2 = {-xx[8], -xx[9], -xx[10], -xx[11]};
        float4 v3 = {-xx[12], -xx[13], -xx[14], -xx[15]};
        dst[0] = v0; dst[1] = v1; dst[2] = v2; dst[3] = v3;
        float s = 0.f;
#pragma unroll
        for (int i = 0; i < 16; ++i) s += U.bw.qt[32 + i] * xx[i];
        dAcc -= 0.5f * s;
      }
      {  // vn = qx + Qxu*kt using local xx (kt lives in lane 32's xx)
        float acc = 0.f;
        bf16x8 xh0, xh1, xl0, xl1;
        if (lane < 32) {
          xh0 = *(const bf16x8*)&U.bw.Xh[lane][0];
          xh1 = *(const bf16x8*)&U.bw.Xh[lane][8];
          xl0 = *(const bf16x8*)&U.bw.Xl[lane][0];
          xl1 = *(const bf16x8*)&U.bw.Xl[lane][8];
          acc = U.bw.qt[lane];
        }
#pragma unroll
        for (int u = 0; u < 8; ++u) {
          float kt0 = -rdl(xx[u], 32);
          float kt1 = -rdl(xx[8 + u], 32);
          if (lane < 32) {
            acc += ((float)xh0[u] + (float)xl0[u]) * kt0;
            acc += ((float)xh1[u] + (float)xl1[u]) * kt1;
          }
        }
        if (lane < 32) U.bw.vv[lane] = acc;
      }
      // P4 on the solver wave: KT just written by this wave (lgkm dep only)
      {  // V(0,0) = Qd[0] + Xrows0-15 · KTcols0-15
        bf16x8 aH = *(const bf16x8*)&U.bw.Xh[fn][k0];
        bf16x8 aL = *(const bf16x8*)&U.bw.Xl[fn][k0];
        bf16x8 bH = *(const bf16x8*)&U.bw.KTh[fn][k0];
        bf16x8 bL = *(const bf16x8*)&U.bw.KTl[fn][k0];
        f32x4 acc;
#pragma unroll
        for (int r = 0; r < 4; ++r) acc[r] = U.bw.Qd[0][4 * quad + r][fn];
        acc = MFMA16(aL, bH, acc);
        acc = MFMA16(aH, bL, acc);
        acc = MFMA16(aH, bH, acc);
#pragma unroll
        for (int r = 0; r < 4; ++r) {
          float v = acc[r];
          __bf16 h = (__bf16)v;
          U.bw.Vh[4 * quad + r][fn] = h;
          U.bw.Vl[4 * quad + r][fn] = (__bf16)(v - (float)h);
        }
      }
      {  // V(1,1) = Qd[2] + Xrows16-31 · KTcols16-31
        bf16x8 aH = *(const bf16x8*)&U.bw.Xh[16 + fn][k0];
        bf16x8 aL = *(const bf16x8*)&U.bw.Xl[16 + fn][k0];
        bf16x8 bH = *(const bf16x8*)&U.bw.KTh[16 + fn][k0];
        bf16x8 bL = *(const bf16x8*)&U.bw.KTl[16 + fn][k0];
        f32x4 acc;
#pragma unroll
        for (int r = 0; r < 4; ++r) acc[r] = U.bw.Qd[2][4 * quad + r][fn];
        acc = MFMA16(aL, bH, acc);
        acc = MFMA16(aH, bL, acc);
        acc = MFMA16(aH, bH, acc);
#pragma unroll
        for (int r = 0; r < 4; ++r) {
          float v = acc[r];
          __bf16 h = (__bf16)v;
          U.bw.Vh[16 + 4 * quad + r][16 + fn] = h;
          U.bw.Vl[16 + 4 * quad + r][16 + fn] = (__bf16)(v - (float)h);
        }
      }
      {  // V(0,1) = Qd[1] + Xrows0-15 · KTcols16-31, plus symmetric mirror
        bf16x8 aH = *(const bf16x8*)&U.bw.Xh[fn][k0];
        bf16x8 aL = *(const bf16x8*)&U.bw.Xl[fn][k0];
        bf16x8 bH = *(const bf16x8*)&U.bw.KTh[16 + fn][k0];
        bf16x8 bL = *(const bf16x8*)&U.bw.KTl[16 + fn][k0];
        f32x4 acc;
#pragma unroll
        for (int r = 0; r < 4; ++r) acc[r] = U.bw.Qd[1][4 * quad + r][fn];
        acc = MFMA16(aL, bH, acc);
        acc = MFMA16(aH, bL, acc);
        acc = MFMA16(aH, bH, acc);
        bf16x4 th, tl;
#pragma unroll
        for (int r = 0; r < 4; ++r) {
          float v = acc[r];
          __bf16 h = (__bf16)v;
          __bf16 l = (__bf16)(v - (float)h);
          U.bw.Vh[4 * quad + r][16 + fn] = h;
          U.bw.Vl[4 * quad + r][16 + fn] = l;
          th[r] = h; tl[r] = l;
        }
        *(bf16x4*)&U.bw.Vh[16 + fn][4 * quad] = th;  // mirror (V symmetric)
        *(bf16x4*)&U.bw.Vl[16 + fn][4 * quad] = tl;
      }
    }
    bar_lgkm();  // B3 (end of step)
  }

  // ---------------- cost partial, then union flips to forward ----------------
  if (w == 3) {
    float rv = (lane < 32) ? cAcc : (lane == 32 ? dAcc : 0.f);
    rv += __shfl_down(rv, 32);
    rv += __shfl_down(rv, 16);
    rv += __shfl_down(rv, 8);
    rv += __shfl_down(rv, 4);
    rv += __shfl_down(rv, 2);
    rv += __shfl_down(rv, 1);
    if (lane == 0) scostp[0] = rv;
  }
  // Full __syncthreads: drains wsK/wskv global stores (forward reads them via
  // global) and fences union re-use.
  __syncthreads();

  // ---------------- forward: wave-0 synchronous, barrier-free ----------------
  if (w == 0) {
    {  // preload K_0, k_0 into buf 0 (transposed, stride 36)
      const float4* src = (const float4*)(wsK + ((size_t)b * Td) * 512);
      float4 ka = src[lane * 2], kb = src[lane * 2 + 1];
      int jj = lane >> 1, ib = (lane & 1) * 8;
      float* kt2 = U.fw.K2T[0];
      kt2[(ib + 0) * 36 + jj] = ka.x; kt2[(ib + 1) * 36 + jj] = ka.y;
      kt2[(ib + 2) * 36 + jj] = ka.z; kt2[(ib + 3) * 36 + jj] = ka.w;
      kt2[(ib + 4) * 36 + jj] = kb.x; kt2[(ib + 5) * 36 + jj] = kb.y;
      kt2[(ib + 6) * 36 + jj] = kb.z; kt2[(ib + 7) * 36 + jj] = kb.w;
      if (lane < 16) U.fw.kv2[0][lane] = wskv[(size_t)b * Td * 16 + lane];
    }
    float xr = (lane < 32) ? scx[0][lane] : 0.f;
    for (int t = 0; t < Td; ++t) {
      const int cur = t & 1, nxt = cur ^ 1;
      float4 pa, pb;
      float pk;
      if (t < Td - 1) {  // prefetch K_{t+1}
        const float4* src = (const float4*)(wsK + ((size_t)b * Td + t + 1) * 512);
        pa = src[lane * 2];
        pb = src[lane * 2 + 1];
        if (lane < 16) pk = wskv[((size_t)b * Td + t + 1) * 16 + lane];
      }
      if (lane < 32) {  // d = x - cx; stash x; emit x
        U.fw.d[lane] = xr - scx[t][lane];
        U.fw.xs[lane] = xr;
        out[XOFF + ((size_t)b * Td + t) * 32 + lane] = xr;
      }
      if (lane < 16) {  // u = k + K d; emit u
        float uv = U.fw.kv2[cur][lane];
        const float* kr = &U.fw.K2T[cur][lane * 36];
#pragma unroll
        for (int j4 = 0; j4 < 8; ++j4) {
          float4 kk = *(const float4*)&kr[j4 * 4];
          float4 dd = *(const float4*)&U.fw.d[j4 * 4];
          uv += kk.x * dd.x + kk.y * dd.y + kk.z * dd.z + kk.w * dd.w;
        }
        U.fw.uu[lane] = uv;
        out[UOFF + ((size_t)b * Td + t) * 16 + lane] = uv;
      }
      if (lane < 32) {  // x' = A x + B u
        float acc = 0.f;
#pragma unroll
        for (int j4 = 0; j4 < 8; ++j4) {
          float4 ff = *(const float4*)&sFf[lane][j4 * 4];
          float4 xv = *(const float4*)&U.fw.xs[j4 * 4];
          acc += ff.x * xv.x + ff.y * xv.y + ff.z * xv.z + ff.w * xv.w;
        }
#pragma unroll
        for (int j4 = 0; j4 < 4; ++j4) {
          float4 ff = *(const float4*)&sFf[lane][32 + j4 * 4];
          float4 uv = *(const float4*)&U.fw.uu[j4 * 4];
          acc += ff.x * uv.x + ff.y * uv.y + ff.z * uv.z + ff.w * uv.w;
        }
        xr = acc;
      }
      if (t < Td - 1) {  // commit K_{t+1}
        int jj = lane >> 1, ib = (lane & 1) * 8;
        float* kt2 = U.fw.K2T[nxt];
        kt2[(ib + 0) * 36 + jj] = pa.x; kt2[(ib + 1) * 36 + jj] = pa.y;
        kt2[(ib + 2) * 36 + jj] = pa.z; kt2[(ib + 3) * 36 + jj] = pa.w;
        kt2[(ib + 4) * 36 + jj] = pb.x; kt2[(ib + 5) * 36 + jj] = pb.y;
        kt2[(ib + 6) * 36 + jj] = pb.z; kt2[(ib + 7) * 36 + jj] = pb.w;
        if (lane < 16) U.fw.kv2[nxt][lane] = pk;
      }
    }
    if (lane == 0) out[COFF + b] = scostp[0];
  }
}

extern "C" void kernel_launch(void* const* d_in, const int* in_sizes, int n_in,
                              void* d_out, int out_size, void* d_ws, size_t ws_size,
                              hipStream_t stream) {
  const float* x_init = (const float*)d_in[0];
  const float* Qg = (const float*)d_in[1];
  const float* pg = (const float*)d_in[2];
  const float* Ag = (const float*)d_in[3];
  const float* Bg = (const float*)d_in[4];
  float* out = (float*)d_out;
  float* wsK = (float*)d_ws;
  float* wskv = wsK + (size_t)NBd * Td * NSd * NCd;
  lqr_kernel<<<NBd, 256, 0, stream>>>(x_init, Qg, pg, Ag, Bg, out, wsK, wskv);
}